// Round 2
// baseline (137.005 us; speedup 1.0000x reference)
//
#include <hip/hip_runtime.h>
#include <hip/hip_bf16.h>

typedef __bf16 bf16x8 __attribute__((ext_vector_type(8)));
typedef __bf16 bf16x4 __attribute__((ext_vector_type(4)));
typedef float f32x4 __attribute__((ext_vector_type(4)));

#define MFMA16(a, b, c) __builtin_amdgcn_mfma_f32_16x16x32_bf16((a), (b), (c), 0, 0, 0)

constexpr int kB  = 4096;
constexpr int kN  = 49;
constexpr int kC  = 128;
constexpr float kScale = 0.17677669529663687f;  // 32^-0.5

// workspace layout (bytes)
constexpr size_t WQ_OFF = 0;       // qkv_w packed bf16: [24][4][64][8] = 98304 B
constexpr size_t WP_OFF = 98304;   // proj_w packed bf16: [8][4][64][8] = 32768 B
constexpr size_t BP_OFF = 131072;  // bias padded f32:   [4][64][64]    = 65536 B

// ---------------------------------------------------------------------------
// prep: repack weights to bf16 fragment-linear layout + gather rel-pos bias
// ---------------------------------------------------------------------------
__global__ void prep_kernel(const float* __restrict__ qkv_w,
                            const float* __restrict__ proj_w,
                            const float* __restrict__ bias_table,
                            const int* __restrict__ rel_raw,
                            __bf16* __restrict__ wq, __bf16* __restrict__ wp,
                            float* __restrict__ biasp) {
  const int blk = blockIdx.x, t = threadIdx.x;
  if (blk < 24) {  // qkv_w pack, nt = blk
    const int kk = t >> 6, lane = t & 63;
    const int k0 = kk * 32 + ((lane >> 4) << 3);
    const int c  = blk * 16 + (lane & 15);
#pragma unroll
    for (int i = 0; i < 8; ++i)
      wq[((blk * 4 + kk) * 64 + lane) * 8 + i] = (__bf16)qkv_w[(k0 + i) * 384 + c];
  } else if (blk < 32) {  // proj_w pack, nt = blk-24
    const int nt = blk - 24;
    const int kk = t >> 6, lane = t & 63;
    const int k0 = kk * 32 + ((lane >> 4) << 3);
    const int c  = nt * 16 + (lane & 15);
#pragma unroll
    for (int i = 0; i < 8; ++i)
      wp[((nt * 4 + kk) * 64 + lane) * 8 + i] = (__bf16)proj_w[(k0 + i) * 128 + c];
  } else {  // bias gather: blocks 32..95 -> 16384 entries [4][64][64]
    const int e = (blk - 32) * 256 + t;
    const int h = e >> 12, i = (e >> 6) & 63, j = e & 63;
    // sniff int64 vs int32 rel_index: int64 little-endian has zero odd words
    bool is64 = true;
    for (int q = 1; q < 128; q += 2)
      if (rel_raw[q] != 0) { is64 = false; break; }
    float v = 0.f;
    if (i < kN && j < kN) {
      const int flat = i * kN + j;
      const int idx = is64 ? rel_raw[2 * flat] : rel_raw[flat];
      v = bias_table[idx * 4 + h];
    }
    biasp[(h * 64 + i) * 64 + j] = v;
  }
}

// ---------------------------------------------------------------------------
// fused window attention: 1 block = 1 window (49 tokens), 4 waves = 4 heads
// ---------------------------------------------------------------------------
__global__ __launch_bounds__(256, 2)
void wattn_fused(const float* __restrict__ x, const float* __restrict__ mask,
                 const float* __restrict__ qkv_b, const float* __restrict__ proj_b,
                 const __bf16* __restrict__ wq, const __bf16* __restrict__ wp,
                 const float* __restrict__ biasp, float* __restrict__ out) {
  constexpr int XS = 136;  // xb/ob row stride (bf16 elems)
  constexpr int QS = 40;   // qs/ks row stride
  constexpr int VS = 72;   // vt row stride (key dim)
  constexpr int PS = 72;   // ps row stride (key dim)

  __shared__ __align__(16) char smem[76800];
  __bf16* xb = (__bf16*)smem;                    // [64][136]; reused as ob
  __bf16* qs = (__bf16*)(smem + 17408);          // [4][64][40]
  __bf16* ks = qs + 4 * 64 * QS;                 // [4][64][40]
  __bf16* ps = qs;                               // overlay after barrier: [4][64][72]
  __bf16* vt = (__bf16*)(smem + 17408 + 40960);  // [4][32][72]

  const int tid  = threadIdx.x;
  const int w    = tid >> 6;
  const int lane = tid & 63;
  const int lg   = lane >> 4;
  const int lm   = lane & 15;
  const int b    = blockIdx.x;

  const f32x4 zero4 = {0.f, 0.f, 0.f, 0.f};

  // ---- phase 1: load x -> xb (bf16), zero pad rows 49..63 ----
  {
    const float* xp = x + (size_t)b * (kN * kC);
    for (int it = tid; it < (kN * kC) / 4; it += 256) {  // 1568 quads
      f32x4 v = *(const f32x4*)(xp + it * 4);
      const int row = it >> 5, col = (it & 31) << 2;
      bf16x4 hv;
      hv[0] = (__bf16)v[0]; hv[1] = (__bf16)v[1];
      hv[2] = (__bf16)v[2]; hv[3] = (__bf16)v[3];
      *(bf16x4*)(xb + row * XS + col) = hv;
    }
    for (int it = tid; it < 15 * 34; it += 256) {  // zero rows 49..63
      const int row = 49 + it / 34, col = (it % 34) * 4;
      bf16x4 z; z[0] = (__bf16)0.f; z[1] = (__bf16)0.f; z[2] = (__bf16)0.f; z[3] = (__bf16)0.f;
      *(bf16x4*)(xb + row * XS + col) = z;
    }
  }
  __syncthreads();

  // ---- phase 2: QKV GEMM [64x128]@[128x384] -> qs/ks/vt (bf16) ----
  {
    bf16x8 af[4][4];
#pragma unroll
    for (int mt = 0; mt < 4; ++mt)
#pragma unroll
      for (int kk = 0; kk < 4; ++kk)
        af[mt][kk] = *(const bf16x8*)(xb + (mt * 16 + lm) * XS + kk * 32 + lg * 8);

    for (int n = 0; n < 6; ++n) {
      const int ntg = w * 6 + n;
      bf16x8 bfr[4];
#pragma unroll
      for (int kk = 0; kk < 4; ++kk)
        bfr[kk] = *(const bf16x8*)(wq + ((ntg * 4 + kk) * 64 + lane) * 8);
      f32x4 acc[4];
#pragma unroll
      for (int mt = 0; mt < 4; ++mt) acc[mt] = zero4;
#pragma unroll
      for (int kk = 0; kk < 4; ++kk)
#pragma unroll
        for (int mt = 0; mt < 4; ++mt)
          acc[mt] = MFMA16(af[mt][kk], bfr[kk], acc[mt]);

      const int c = ntg * 16 + lm;
      const int which = c >> 7;
      const int h = (c >> 5) & 3;
      const int d = c & 31;
      const float qb = qkv_b[c];
      if (which == 0) {
#pragma unroll
        for (int mt = 0; mt < 4; ++mt)
#pragma unroll
          for (int j = 0; j < 4; ++j)
            qs[(h * 64 + mt * 16 + lg * 4 + j) * QS + d] =
                (__bf16)((acc[mt][j] + qb) * kScale);
      } else if (which == 1) {
#pragma unroll
        for (int mt = 0; mt < 4; ++mt)
#pragma unroll
          for (int j = 0; j < 4; ++j)
            ks[(h * 64 + mt * 16 + lg * 4 + j) * QS + d] = (__bf16)(acc[mt][j] + qb);
      } else {  // V stored transposed: vt[h][d][key]
#pragma unroll
        for (int mt = 0; mt < 4; ++mt) {
          const int r0 = mt * 16 + lg * 4;
          bf16x4 pv;
#pragma unroll
          for (int j = 0; j < 4; ++j) pv[j] = (__bf16)(acc[mt][j] + qb);
          *(bf16x4*)(vt + (h * 32 + d) * VS + r0) = pv;
        }
      }
    }
  }
  __syncthreads();

  // ---- phase 3: per-head attention (wave w = head w) ----
  f32x4 s[4][4];
  {
    const int h = w;
    const __bf16* qsh = qs + h * 64 * QS;
    const __bf16* ksh = ks + h * 64 * QS;
    bf16x8 qf[4], kf[4];
#pragma unroll
    for (int mt = 0; mt < 4; ++mt)
      qf[mt] = *(const bf16x8*)(qsh + (mt * 16 + lm) * QS + lg * 8);
#pragma unroll
    for (int nt = 0; nt < 4; ++nt)
      kf[nt] = *(const bf16x8*)(ksh + (nt * 16 + lm) * QS + lg * 8);
#pragma unroll
    for (int mt = 0; mt < 4; ++mt)
#pragma unroll
      for (int nt = 0; nt < 4; ++nt)
        s[mt][nt] = MFMA16(qf[mt], kf[nt], zero4);

    const float* bp = biasp + h * 4096;
    const float* mk = mask + (size_t)(b & 63) * (kN * kN);
#pragma unroll
    for (int mt = 0; mt < 4; ++mt)
#pragma unroll
      for (int nt = 0; nt < 4; ++nt)
#pragma unroll
        for (int j = 0; j < 4; ++j) {
          const int r = mt * 16 + lg * 4 + j, cc = nt * 16 + lm;
          float v = s[mt][nt][j] + bp[(r << 6) + cc];
          if (cc < kN) {
            if (r < kN) v += mk[r * kN + cc];
          } else {
            v = -1e30f;
          }
          s[mt][nt][j] = v;
        }
    // softmax over keys (row lives in 16 lanes x 4 nt-tiles)
#pragma unroll
    for (int mt = 0; mt < 4; ++mt) {
      f32x4 pm;
#pragma unroll
      for (int j = 0; j < 4; ++j)
        pm[j] = fmaxf(fmaxf(s[mt][0][j], s[mt][1][j]), fmaxf(s[mt][2][j], s[mt][3][j]));
#pragma unroll
      for (int off = 1; off <= 8; off <<= 1)
#pragma unroll
        for (int j = 0; j < 4; ++j)
          pm[j] = fmaxf(pm[j], __shfl_xor(pm[j], off, 64));
      f32x4 sum = zero4;
#pragma unroll
      for (int nt = 0; nt < 4; ++nt)
#pragma unroll
        for (int j = 0; j < 4; ++j) {
          const float e = __expf(s[mt][nt][j] - pm[j]);
          s[mt][nt][j] = e;
          sum[j] += e;
        }
#pragma unroll
      for (int off = 1; off <= 8; off <<= 1)
#pragma unroll
        for (int j = 0; j < 4; ++j) sum[j] += __shfl_xor(sum[j], off, 64);
#pragma unroll
      for (int j = 0; j < 4; ++j) pm[j] = 1.f / sum[j];
#pragma unroll
      for (int nt = 0; nt < 4; ++nt)
#pragma unroll
        for (int j = 0; j < 4; ++j) s[mt][nt][j] *= pm[j];
    }
  }
  __syncthreads();  // all waves done reading qs/ks -> safe to overlay with ps

  // ---- phase 3b: P -> LDS, PV, scatter to ob (= xb region) ----
  {
    const int h = w;
    __bf16* psh = ps + h * 64 * PS;
    const __bf16* vth = vt + h * 32 * VS;
#pragma unroll
    for (int mt = 0; mt < 4; ++mt)
#pragma unroll
      for (int nt = 0; nt < 4; ++nt)
#pragma unroll
        for (int j = 0; j < 4; ++j)
          psh[(mt * 16 + lg * 4 + j) * PS + nt * 16 + lm] = (__bf16)s[mt][nt][j];

    f32x4 o[4][2];
#pragma unroll
    for (int mt = 0; mt < 4; ++mt)
#pragma unroll
      for (int n2 = 0; n2 < 2; ++n2) o[mt][n2] = zero4;
#pragma unroll
    for (int kk = 0; kk < 2; ++kk) {
      bf16x8 vf[2];
#pragma unroll
      for (int n2 = 0; n2 < 2; ++n2)
        vf[n2] = *(const bf16x8*)(vth + (n2 * 16 + lm) * VS + kk * 32 + lg * 8);
#pragma unroll
      for (int mt = 0; mt < 4; ++mt) {
        bf16x8 pf = *(const bf16x8*)(psh + (mt * 16 + lm) * PS + kk * 32 + lg * 8);
#pragma unroll
        for (int n2 = 0; n2 < 2; ++n2) o[mt][n2] = MFMA16(pf, vf[n2], o[mt][n2]);
      }
    }
#pragma unroll
    for (int mt = 0; mt < 4; ++mt)
#pragma unroll
      for (int n2 = 0; n2 < 2; ++n2)
#pragma unroll
        for (int j = 0; j < 4; ++j)
          xb[(mt * 16 + lg * 4 + j) * XS + h * 32 + n2 * 16 + lm] =
              (__bf16)o[mt][n2][j];
  }
  __syncthreads();

  // ---- phase 4: proj GEMM [64x128]@[128x128] + bias -> out (f32) ----
  {
    bf16x8 paf[4][4];
#pragma unroll
    for (int mt = 0; mt < 4; ++mt)
#pragma unroll
      for (int kk = 0; kk < 4; ++kk)
        paf[mt][kk] = *(const bf16x8*)(xb + (mt * 16 + lm) * XS + kk * 32 + lg * 8);

    float* op = out + (size_t)b * (kN * kC);
#pragma unroll
    for (int n = 0; n < 2; ++n) {
      const int ntg = w * 2 + n;
      bf16x8 bfr[4];
#pragma unroll
      for (int kk = 0; kk < 4; ++kk)
        bfr[kk] = *(const bf16x8*)(wp + ((ntg * 4 + kk) * 64 + lane) * 8);
      f32x4 acc[4];
#pragma unroll
      for (int mt = 0; mt < 4; ++mt) acc[mt] = zero4;
#pragma unroll
      for (int kk = 0; kk < 4; ++kk)
#pragma unroll
        for (int mt = 0; mt < 4; ++mt)
          acc[mt] = MFMA16(paf[mt][kk], bfr[kk], acc[mt]);
      const int cc = ntg * 16 + lm;
      const float pb = proj_b[cc];
#pragma unroll
      for (int mt = 0; mt < 4; ++mt)
#pragma unroll
        for (int j = 0; j < 4; ++j) {
          const int r = mt * 16 + lg * 4 + j;
          if (r < kN) op[r * kC + cc] = acc[mt][j] + pb;
        }
    }
  }
}

// ---------------------------------------------------------------------------
extern "C" void kernel_launch(void* const* d_in, const int* in_sizes, int n_in,
                              void* d_out, int out_size, void* d_ws, size_t ws_size,
                              hipStream_t stream) {
  const float* x          = (const float*)d_in[0];
  const float* mask       = (const float*)d_in[1];
  const float* qkv_w      = (const float*)d_in[2];
  const float* qkv_b      = (const float*)d_in[3];
  const float* proj_w     = (const float*)d_in[4];
  const float* proj_b     = (const float*)d_in[5];
  const float* bias_table = (const float*)d_in[6];
  const int*   rel        = (const int*)d_in[7];

  char* ws = (char*)d_ws;
  __bf16* wq   = (__bf16*)(ws + WQ_OFF);
  __bf16* wp   = (__bf16*)(ws + WP_OFF);
  float* biasp = (float*)(ws + BP_OFF);

  prep_kernel<<<96, 256, 0, stream>>>(qkv_w, proj_w, bias_table, rel, wq, wp, biasp);
  wattn_fused<<<kB, 256, 0, stream>>>(x, mask, qkv_b, proj_b, wq, wp, biasp,
                                      (float*)d_out);
}